// Round 8
// baseline (235.014 us; speedup 1.0000x reference)
//
#include <hip/hip_runtime.h>
#include <hip/hip_bf16.h>

typedef __attribute__((ext_vector_type(4))) float f32x4;
typedef __attribute__((ext_vector_type(16))) float f32x16;
typedef __attribute__((ext_vector_type(8))) short short8;
typedef __attribute__((ext_vector_type(4))) short short4v;
typedef unsigned short ushort_t;

#define BATCH 256
#define PDIM 512
#define MDIM 768
#define XCOLS 1280
#define PROJ 512
#define HID 256
#define KTOT (PDIM * MDIM)

#define BN 32
#define NT 16       // N tiles (512/32)
#define PSPLIT 32   // pi splits (was 64: halves partial-ws, atomics, stream count)
#define PI_PER 16   // 512/32
#define NJW 12      // j windows of 64
#define NSTEPS 192  // PI_PER * NJW ; pil = s&15 (inner), jw = s>>4

__device__ __forceinline__ ushort_t f2bf(float f) {
  __hip_bfloat16 h = __float2bfloat16(f);
  return __builtin_bit_cast(ushort_t, h);
}
__device__ __forceinline__ float bf2f(ushort_t u) {
  union { unsigned int i; float f; } c;
  c.i = ((unsigned int)u) << 16;
  return c.f;
}

// ---------------- prep: fragment-ordered bf16(m) ----------------
// mF chunk c = ((jw*8 + mf)*4 + ks)*64 + lane ; element e of chunk:
//   bf16( m[row = mf*32+(lane&31)][k = jw*64 + ks*16 + (lane>>5)*8 + e] )
__global__ void prep_kernel(const float* __restrict__ x, ushort_t* __restrict__ mF) {
  int tid = blockIdx.x * blockDim.x + threadIdx.x;
  int nth = gridDim.x * blockDim.x;
  for (int c = tid; c < NJW * 8 * 4 * 64; c += nth) {
    int lane = c & 63;
    int ks = (c >> 6) & 3;
    int mf = (c >> 8) & 7;
    int jw = c >> 11;
    int row = mf * 32 + (lane & 31);
    int k0 = jw * 64 + ks * 16 + ((lane >> 5) << 3);
    const float* src = x + row * XCOLS + PDIM + k0;
    f32x4 v0 = *(const f32x4*)src;
    f32x4 v1 = *(const f32x4*)(src + 4);
    short8 o;
#pragma unroll
    for (int i = 0; i < 4; ++i) {
      o[i] = (short)f2bf(v0[i]);
      o[i + 4] = (short)f2bf(v1[i]);
    }
    ((short8*)mF)[c] = o;
  }
}

// ---------------- main einsum GEMM ----------------
// 512-thread WG, 8 waves, wave tile 32(batch)x32(n), one f32x16 acc.
// ~70 live VGPRs (no spill at cap 128). W1 staged line-dense (each wave
// instr = 4 rows x 256B contiguous), depth-2 prefetch, compiler waits.
// B-LDS in FRAGMENT ORDER (conflict-free ds_read_b128; minor 8-way on the
// single b64 write). A frags in regs from fragment-ordered mF (reload/jw).
__global__ __launch_bounds__(512, 4)
void einsum_kernel(const float* __restrict__ W1, const ushort_t* __restrict__ mF,
                   const float* __restrict__ x, float* __restrict__ outp,
                   int atomic_mode) {
  __shared__ ushort_t Bf[2][2048];      // 2 x 4 KB B frags (frag order)
  __shared__ float pl[PI_PER * BATCH];  // 16 KB p[pil][b]

  const int ntile = blockIdx.x & 15;
  const int ps    = blockIdx.x >> 4;
  const int pi0   = ps * PI_PER;
  const int n0    = ntile * BN;
  const int t     = threadIdx.x;
  const int lane  = t & 63;
  const int w     = t >> 6;   // 8 waves; wave w owns batch rows 32w..32w+31

  // stage p: thread t -> batch row t&255, pi half t>>8 (8 floats)
  {
    const int b = t & 255, half = t >> 8;
    const float* xr = x + (size_t)b * XCOLS + pi0 + half * 8;
    f32x4 v0 = *(const f32x4*)xr;
    f32x4 v1 = *(const f32x4*)(xr + 4);
#pragma unroll
    for (int i = 0; i < 4; ++i) {
      pl[(half * 8 + i) * BATCH + b]     = v0[i];
      pl[(half * 8 + 4 + i) * BATCH + b] = v1[i];
    }
  }

  // W1 staging: r = t>>4 (row 0..31), q2 = t&15 (16-B unit of the 256-B chunk)
  const int r = t >> 4, q2 = t & 15;
  const float* wrow = W1 + (size_t)(n0 + r) * KTOT + (size_t)pi0 * MDIM + q2 * 4;
  // fragment-order write byte offset: ks=q2>>2, hi=(q2>>1)&1, half=q2&1
  const int wb = (((q2 >> 2) * 64) + (((q2 >> 1) & 1) << 5) + r) * 16 + ((q2 & 1) << 3);

  // A fragment chunks in regs: chunk = jw*2048 + w*256 + ks*64 + lane
  const short8* mv = (const short8*)mF;
  const int mbase = w * 256 + lane;
  short8 ac0 = mv[mbase];
  short8 ac1 = mv[mbase + 64];
  short8 ac2 = mv[mbase + 128];
  short8 ac3 = mv[mbase + 192];

  // depth-2 W1 prefetch: wv = s, nv = s+1
  f32x4 wv = __builtin_nontemporal_load((const f32x4*)wrow);
  f32x4 nv = __builtin_nontemporal_load((const f32x4*)(wrow + MDIM));

  f32x16 fa;
#pragma unroll
  for (int i = 0; i < 16; ++i) fa[i] = 0.f;

  __syncthreads();  // pl + prologue visibility

  for (int s = 0; s < NSTEPS; ++s) {
    // ---- issue W1(s+2); compiler-counted waits keep it in flight ----
    int s2 = s + 2; if (s2 >= NSTEPS) s2 -= NSTEPS;
    const int kk2 = (s2 & 15) * MDIM + (s2 >> 4) * 64;
    f32x4 xv = __builtin_nontemporal_load((const f32x4*)(wrow + kk2));

    // ---- cvt W1(s) -> bf16, one frag-order b64 write ----
    {
      short4v o;
#pragma unroll
      for (int i = 0; i < 4; ++i) o[i] = (short)f2bf(wv[i]);
      *(short4v*)((char*)&Bf[s & 1][0] + wb) = o;
    }
    asm volatile("s_waitcnt lgkmcnt(0)" ::: "memory");
    __builtin_amdgcn_s_barrier();
    asm volatile("" ::: "memory");

    // ---- B frags (conflict-free: byte = chunk*16, chunk = ks*64+lane) ----
    const short8* rb = (const short8*)&Bf[s & 1][0];
    const float pa = pl[(s & 15) * BATCH + w * 32 + (lane & 31)];

#define GENMM(ac, ks)                                                  \
    {                                                                  \
      short8 bv = rb[(ks) * 64 + lane];                                \
      short8 aA;                                                       \
      _Pragma("unroll")                                                \
      for (int e = 0; e < 8; ++e)                                      \
        aA[e] = (short)f2bf(pa * bf2f((ushort_t)ac[e]));               \
      fa = __builtin_amdgcn_mfma_f32_32x32x16_bf16(aA, bv, fa, 0, 0, 0); \
    }
    GENMM(ac0, 0)
    GENMM(ac1, 1)
    GENMM(ac2, 2)
    GENMM(ac3, 3)
#undef GENMM

    // ---- jw boundary: reload A frags for next jw (L2-hot, 1 step to land) ----
    if ((s & 15) == 15) {
      int jn = (s >> 4) + 1; if (jn >= NJW) jn = 0;
      const short8* srcn = mv + jn * 2048 + mbase;
      ac0 = srcn[0];
      ac1 = srcn[64];
      ac2 = srcn[128];
      ac3 = srcn[192];
    }
    wv = nv; nv = xv;
  }

  // ---- C write: row = 32w + (rr&3)+8*(rr>>2)+4*(lane>>5), col = n0+(lane&31) ----
  const int col = n0 + (lane & 31);
  const int rb2 = w * 32 + ((lane >> 5) << 2);
  if (atomic_mode) {
#pragma unroll
    for (int rr = 0; rr < 16; ++rr) {
      int row = rb2 + (rr & 3) + ((rr >> 2) << 3);
      atomicAdd(&outp[(size_t)row * PROJ + col], fa[rr]);
    }
  } else {
    float* dst = outp + (size_t)ps * BATCH * PROJ;
#pragma unroll
    for (int rr = 0; rr < 16; ++rr) {
      int row = rb2 + (rr & 3) + ((rr >> 2) << 3);
      dst[(size_t)row * PROJ + col] = fa[rr];
    }
  }
}

// ---------------- reduce + LN + MLP ----------------
__global__ __launch_bounds__(256)
void mlp_kernel(const float* __restrict__ part, int nps,
                const float* __restrict__ b1, const float* __restrict__ lng,
                const float* __restrict__ lnb, const float* __restrict__ W2,
                const float* __restrict__ b2, const float* __restrict__ g1,
                const float* __restrict__ bb1, const float* __restrict__ W3,
                const float* __restrict__ b3, const float* __restrict__ g2,
                const float* __restrict__ bb2, const float* __restrict__ W4,
                const float* __restrict__ b4, float* __restrict__ out) {
  __shared__ float h1[PROJ];
  __shared__ float h2[HID];
  __shared__ float h3[HID / 2];
  __shared__ float red[16];
  const int b = blockIdx.x, t = threadIdx.x;

  float f0 = 0.f, f1 = 0.f;
  const float* p0 = part + (size_t)b * PROJ + t;
#pragma unroll 4
  for (int s = 0; s < nps; ++s) {
    f0 += p0[0];
    f1 += p0[256];
    p0 += (size_t)BATCH * PROJ;
  }
  f0 += b1[t];
  f1 += b1[t + 256];

  float sum = f0 + f1, ss = f0 * f0 + f1 * f1;
#pragma unroll
  for (int o = 32; o > 0; o >>= 1) {
    sum += __shfl_xor(sum, o);
    ss  += __shfl_xor(ss, o);
  }
  const int wv = t >> 6, ln = t & 63;
  if (ln == 0) { red[wv] = sum; red[8 + wv] = ss; }
  __syncthreads();
  sum = red[0] + red[1] + red[2] + red[3];
  ss  = red[8] + red[9] + red[10] + red[11];
  float mu   = sum * (1.f / 512.f);
  float var  = ss * (1.f / 512.f) - mu * mu;
  float rstd = rsqrtf(var + 1e-5f);
  h1[t]       = fmaxf(0.f, (f0 - mu) * rstd * lng[t] + lnb[t]);
  h1[t + 256] = fmaxf(0.f, (f1 - mu) * rstd * lng[t + 256] + lnb[t + 256]);
  __syncthreads();

  const float bninv = rsqrtf(1.f + 1e-5f);
  {
    const f32x4* wr = (const f32x4*)(W2 + (size_t)t * PROJ);
    const f32x4* hv = (const f32x4*)h1;
    float a = 0.f;
#pragma unroll 4
    for (int i = 0; i < PROJ / 4; ++i) {
      f32x4 wq = wr[i], h = hv[i];
      a += wq[0] * h[0] + wq[1] * h[1] + wq[2] * h[2] + wq[3] * h[3];
    }
    h2[t] = fmaxf(0.f, (a + b2[t]) * bninv * g1[t] + bb1[t]);
  }
  __syncthreads();
  if (t < 128) {
    const f32x4* wr = (const f32x4*)(W3 + (size_t)t * HID);
    const f32x4* hv = (const f32x4*)h2;
    float a = 0.f;
#pragma unroll 4
    for (int i = 0; i < HID / 4; ++i) {
      f32x4 wq = wr[i], h = hv[i];
      a += wq[0] * h[0] + wq[1] * h[1] + wq[2] * h[2] + wq[3] * h[3];
    }
    h3[t] = fmaxf(0.f, (a + b3[t]) * bninv * g2[t] + bb2[t]);
  }
  __syncthreads();
  if (t < 2) {
    const float* wr = W4 + t * 128;
    float a = 0.f;
#pragma unroll 4
    for (int i = 0; i < 128; ++i) a += wr[i] * h3[i];
    out[b * 2 + t] = a + b4[t];
  }
}

extern "C" void kernel_launch(void* const* d_in, const int* in_sizes, int n_in,
                              void* d_out, int out_size, void* d_ws, size_t ws_size,
                              hipStream_t stream) {
  const float* x   = (const float*)d_in[0];
  const float* W1  = (const float*)d_in[1];
  const float* b1  = (const float*)d_in[2];
  const float* lng = (const float*)d_in[3];
  const float* lnb = (const float*)d_in[4];
  const float* W2  = (const float*)d_in[5];
  const float* b2  = (const float*)d_in[6];
  const float* g1  = (const float*)d_in[7];
  const float* bb1 = (const float*)d_in[8];
  const float* W3  = (const float*)d_in[9];
  const float* b3  = (const float*)d_in[10];
  const float* g2  = (const float*)d_in[11];
  const float* bb2 = (const float*)d_in[12];
  const float* W4  = (const float*)d_in[13];
  const float* b4  = (const float*)d_in[14];
  float* out = (float*)d_out;

  char* ws = (char*)d_ws;
  ushort_t* mF = (ushort_t*)ws;              // 384 KB (fragment-ordered bf16 m)
  float* big   = (float*)(ws + 524288);      // split-K partials

  size_t need = 524288 + (size_t)PSPLIT * BATCH * PROJ * 4;  // ~17.3 MB
  bool partial = ws_size >= need;

  hipLaunchKernelGGL(prep_kernel, dim3(256), dim3(256), 0, stream, x, mF);
  if (partial) {
    hipLaunchKernelGGL(einsum_kernel, dim3(NT * PSPLIT), dim3(512), 0, stream,
                       W1, mF, x, big, 0);
    hipLaunchKernelGGL(mlp_kernel, dim3(BATCH), dim3(256), 0, stream, big, PSPLIT,
                       b1, lng, lnb, W2, b2, g1, bb1, W3, b3, g2, bb2, W4, b4, out);
  } else {
    hipMemsetAsync(big, 0, (size_t)BATCH * PROJ * 4, stream);
    hipLaunchKernelGGL(einsum_kernel, dim3(NT * PSPLIT), dim3(512), 0, stream,
                       W1, mF, x, big, 1);
    hipLaunchKernelGGL(mlp_kernel, dim3(BATCH), dim3(256), 0, stream, big, 1,
                       b1, lng, lnb, W2, b2, g1, bb1, W3, b3, g2, bb2, W4, b4, out);
  }
}

// Round 9
// 224.834 us; speedup vs baseline: 1.0453x; 1.0453x over previous
//
#include <hip/hip_runtime.h>
#include <hip/hip_bf16.h>

typedef __attribute__((ext_vector_type(4))) float f32x4;
typedef __attribute__((ext_vector_type(16))) float f32x16;
typedef __attribute__((ext_vector_type(8))) short short8;
typedef __attribute__((ext_vector_type(4))) short short4v;
typedef unsigned short ushort_t;

#define BATCH 256
#define PDIM 512
#define MDIM 768
#define XCOLS 1280
#define PROJ 512
#define HID 256
#define KTOT (PDIM * MDIM)

#define BN 32
#define NT 16       // N tiles (512/32)
#define PSPLIT 32   // pi splits
#define PI_PER 16   // 512/32
#define NJW 12      // j windows of 64
#define NSTEPS 192  // PI_PER * NJW ; pil = s&15 (inner), jw = s>>4

__device__ __forceinline__ ushort_t f2bf(float f) {
  __hip_bfloat16 h = __float2bfloat16(f);
  return __builtin_bit_cast(ushort_t, h);
}
__device__ __forceinline__ float bf2f(ushort_t u) {
  union { unsigned int i; float f; } c;
  c.i = ((unsigned int)u) << 16;
  return c.f;
}

// ---------------- prep: fragment-ordered bf16(m) ----------------
// mF chunk c = ((jw*8 + mf)*4 + ks)*64 + lane ; element e of chunk:
//   bf16( m[row = mf*32+(lane&31)][k = jw*64 + ks*16 + (lane>>5)*8 + e] )
__global__ void prep_kernel(const float* __restrict__ x, ushort_t* __restrict__ mF) {
  int tid = blockIdx.x * blockDim.x + threadIdx.x;
  int nth = gridDim.x * blockDim.x;
  for (int c = tid; c < NJW * 8 * 4 * 64; c += nth) {
    int lane = c & 63;
    int ks = (c >> 6) & 3;
    int mf = (c >> 8) & 7;
    int jw = c >> 11;
    int row = mf * 32 + (lane & 31);
    int k0 = jw * 64 + ks * 16 + ((lane >> 5) << 3);
    const float* src = x + row * XCOLS + PDIM + k0;
    f32x4 v0 = *(const f32x4*)src;
    f32x4 v1 = *(const f32x4*)(src + 4);
    short8 o;
#pragma unroll
    for (int i = 0; i < 4; ++i) {
      o[i] = (short)f2bf(v0[i]);
      o[i + 4] = (short)f2bf(v1[i]);
    }
    ((short8*)mF)[c] = o;
  }
}

// ---------------- main einsum GEMM ----------------
// r8 structure with DEPTH-4 W1 register-ring prefetch (in-flight bytes/CU
// 32 KB -> 64 KB, Little's-law fix for loaded HBM latency ~2us). 4-phase
// static unroll keeps ring indices + LDS dbuf selects compile-time.
__global__ __launch_bounds__(512, 4)
void einsum_kernel(const float* __restrict__ W1, const ushort_t* __restrict__ mF,
                   const float* __restrict__ x, float* __restrict__ outp,
                   int atomic_mode) {
  __shared__ ushort_t Bf[2][2048];      // 2 x 4 KB B frags (frag order)
  __shared__ float pl[PI_PER * BATCH];  // 16 KB p[pil][b]

  const int ntile = blockIdx.x & 15;
  const int ps    = blockIdx.x >> 4;
  const int pi0   = ps * PI_PER;
  const int n0    = ntile * BN;
  const int t     = threadIdx.x;
  const int lane  = t & 63;
  const int w     = t >> 6;   // 8 waves; wave w owns batch rows 32w..32w+31

  // stage p: thread t -> batch row t&255, pi half t>>8 (8 floats)
  {
    const int b = t & 255, half = t >> 8;
    const float* xr = x + (size_t)b * XCOLS + pi0 + half * 8;
    f32x4 v0 = *(const f32x4*)xr;
    f32x4 v1 = *(const f32x4*)(xr + 4);
#pragma unroll
    for (int i = 0; i < 4; ++i) {
      pl[(half * 8 + i) * BATCH + b]     = v0[i];
      pl[(half * 8 + 4 + i) * BATCH + b] = v1[i];
    }
  }

  // W1 staging: r = t>>4 (row 0..31), q2 = t&15 (16-B unit of 256-B chunk)
  const int r = t >> 4, q2 = t & 15;
  const float* wrow = W1 + (size_t)(n0 + r) * KTOT + (size_t)pi0 * MDIM + q2 * 4;
  // fragment-order write byte offset: ks=q2>>2, hi=(q2>>1)&1, half=q2&1
  const int wb = (((q2 >> 2) * 64) + (((q2 >> 1) & 1) << 5) + r) * 16 + ((q2 & 1) << 3);

  // A fragment chunks in regs: chunk = jw*2048 + w*256 + ks*64 + lane
  const short8* mv = (const short8*)mF;
  const int mbase = w * 256 + lane;
  short8 ac0 = mv[mbase];
  short8 ac1 = mv[mbase + 64];
  short8 ac2 = mv[mbase + 128];
  short8 ac3 = mv[mbase + 192];

  // depth-4 W1 prefetch ring: pf(i) holds step (it*4 + i)
#define KOFF(s) (((s) & 15) * MDIM + ((s) >> 4) * 64)
  f32x4 pf0 = __builtin_nontemporal_load((const f32x4*)(wrow + KOFF(0)));
  f32x4 pf1 = __builtin_nontemporal_load((const f32x4*)(wrow + KOFF(1)));
  f32x4 pf2 = __builtin_nontemporal_load((const f32x4*)(wrow + KOFF(2)));
  f32x4 pf3 = __builtin_nontemporal_load((const f32x4*)(wrow + KOFF(3)));

  f32x16 fa;
#pragma unroll
  for (int i = 0; i < 16; ++i) fa[i] = 0.f;

  __syncthreads();  // pl visibility

  for (int it = 0; it < NSTEPS / 4; ++it) {
    const int sbase = it * 4;

#define PHASE(PH, PF)                                                        \
    {                                                                        \
      const int scur = sbase + PH;                                           \
      int s4 = scur + 4; if (s4 >= NSTEPS) s4 -= NSTEPS;                     \
      f32x4 newv = __builtin_nontemporal_load((const f32x4*)(wrow + KOFF(s4))); \
      /* cvt W1(scur) -> bf16, one frag-order b64 write */                   \
      {                                                                      \
        short4v o;                                                           \
        _Pragma("unroll")                                                    \
        for (int i = 0; i < 4; ++i) o[i] = (short)f2bf(PF[i]);               \
        *(short4v*)((char*)&Bf[PH & 1][0] + wb) = o;                         \
      }                                                                      \
      asm volatile("s_waitcnt lgkmcnt(0)" ::: "memory");                     \
      __builtin_amdgcn_s_barrier();                                          \
      asm volatile("" ::: "memory");                                         \
      const short8* rb = (const short8*)&Bf[PH & 1][0];                      \
      const float pa = pl[(scur & 15) * BATCH + w * 32 + (lane & 31)];       \
      {                                                                      \
        short8 bv = rb[lane];                                                \
        short8 aA;                                                           \
        _Pragma("unroll")                                                    \
        for (int e = 0; e < 8; ++e)                                          \
          aA[e] = (short)f2bf(pa * bf2f((ushort_t)ac0[e]));                  \
        fa = __builtin_amdgcn_mfma_f32_32x32x16_bf16(aA, bv, fa, 0, 0, 0);   \
      }                                                                      \
      {                                                                      \
        short8 bv = rb[64 + lane];                                           \
        short8 aA;                                                           \
        _Pragma("unroll")                                                    \
        for (int e = 0; e < 8; ++e)                                          \
          aA[e] = (short)f2bf(pa * bf2f((ushort_t)ac1[e]));                  \
        fa = __builtin_amdgcn_mfma_f32_32x32x16_bf16(aA, bv, fa, 0, 0, 0);   \
      }                                                                      \
      {                                                                      \
        short8 bv = rb[128 + lane];                                          \
        short8 aA;                                                           \
        _Pragma("unroll")                                                    \
        for (int e = 0; e < 8; ++e)                                          \
          aA[e] = (short)f2bf(pa * bf2f((ushort_t)ac2[e]));                  \
        fa = __builtin_amdgcn_mfma_f32_32x32x16_bf16(aA, bv, fa, 0, 0, 0);   \
      }                                                                      \
      {                                                                      \
        short8 bv = rb[192 + lane];                                          \
        short8 aA;                                                           \
        _Pragma("unroll")                                                    \
        for (int e = 0; e < 8; ++e)                                          \
          aA[e] = (short)f2bf(pa * bf2f((ushort_t)ac3[e]));                  \
        fa = __builtin_amdgcn_mfma_f32_32x32x16_bf16(aA, bv, fa, 0, 0, 0);   \
      }                                                                      \
      if (PH == 3 && (it & 3) == 3) {    /* scur&15==15: jw boundary */      \
        int jn = (scur >> 4) + 1; if (jn >= NJW) jn = 0;                     \
        const short8* srcn = mv + jn * 2048 + mbase;                         \
        ac0 = srcn[0];                                                       \
        ac1 = srcn[64];                                                      \
        ac2 = srcn[128];                                                     \
        ac3 = srcn[192];                                                     \
      }                                                                      \
      PF = newv;                                                             \
    }

    PHASE(0, pf0)
    PHASE(1, pf1)
    PHASE(2, pf2)
    PHASE(3, pf3)
#undef PHASE
  }
#undef KOFF

  // ---- C write: row = 32w + (rr&3)+8*(rr>>2)+4*(lane>>5), col = n0+(lane&31) ----
  const int col = n0 + (lane & 31);
  const int rb2 = w * 32 + ((lane >> 5) << 2);
  if (atomic_mode) {
#pragma unroll
    for (int rr = 0; rr < 16; ++rr) {
      int row = rb2 + (rr & 3) + ((rr >> 2) << 3);
      atomicAdd(&outp[(size_t)row * PROJ + col], fa[rr]);
    }
  } else {
    float* dst = outp + (size_t)ps * BATCH * PROJ;
#pragma unroll
    for (int rr = 0; rr < 16; ++rr) {
      int row = rb2 + (rr & 3) + ((rr >> 2) << 3);
      dst[(size_t)row * PROJ + col] = fa[rr];
    }
  }
}

// ---------------- reduce + LN + MLP ----------------
__global__ __launch_bounds__(256)
void mlp_kernel(const float* __restrict__ part, int nps,
                const float* __restrict__ b1, const float* __restrict__ lng,
                const float* __restrict__ lnb, const float* __restrict__ W2,
                const float* __restrict__ b2, const float* __restrict__ g1,
                const float* __restrict__ bb1, const float* __restrict__ W3,
                const float* __restrict__ b3, const float* __restrict__ g2,
                const float* __restrict__ bb2, const float* __restrict__ W4,
                const float* __restrict__ b4, float* __restrict__ out) {
  __shared__ float h1[PROJ];
  __shared__ float h2[HID];
  __shared__ float h3[HID / 2];
  __shared__ float red[16];
  const int b = blockIdx.x, t = threadIdx.x;

  float f0 = 0.f, f1 = 0.f;
  const float* p0 = part + (size_t)b * PROJ + t;
#pragma unroll 4
  for (int s = 0; s < nps; ++s) {
    f0 += p0[0];
    f1 += p0[256];
    p0 += (size_t)BATCH * PROJ;
  }
  f0 += b1[t];
  f1 += b1[t + 256];

  float sum = f0 + f1, ss = f0 * f0 + f1 * f1;
#pragma unroll
  for (int o = 32; o > 0; o >>= 1) {
    sum += __shfl_xor(sum, o);
    ss  += __shfl_xor(ss, o);
  }
  const int wv = t >> 6, ln = t & 63;
  if (ln == 0) { red[wv] = sum; red[8 + wv] = ss; }
  __syncthreads();
  sum = red[0] + red[1] + red[2] + red[3];
  ss  = red[8] + red[9] + red[10] + red[11];
  float mu   = sum * (1.f / 512.f);
  float var  = ss * (1.f / 512.f) - mu * mu;
  float rstd = rsqrtf(var + 1e-5f);
  h1[t]       = fmaxf(0.f, (f0 - mu) * rstd * lng[t] + lnb[t]);
  h1[t + 256] = fmaxf(0.f, (f1 - mu) * rstd * lng[t + 256] + lnb[t + 256]);
  __syncthreads();

  const float bninv = rsqrtf(1.f + 1e-5f);
  {
    const f32x4* wr = (const f32x4*)(W2 + (size_t)t * PROJ);
    const f32x4* hv = (const f32x4*)h1;
    float a = 0.f;
#pragma unroll 4
    for (int i = 0; i < PROJ / 4; ++i) {
      f32x4 wq = wr[i], h = hv[i];
      a += wq[0] * h[0] + wq[1] * h[1] + wq[2] * h[2] + wq[3] * h[3];
    }
    h2[t] = fmaxf(0.f, (a + b2[t]) * bninv * g1[t] + bb1[t]);
  }
  __syncthreads();
  if (t < 128) {
    const f32x4* wr = (const f32x4*)(W3 + (size_t)t * HID);
    const f32x4* hv = (const f32x4*)h2;
    float a = 0.f;
#pragma unroll 4
    for (int i = 0; i < HID / 4; ++i) {
      f32x4 wq = wr[i], h = hv[i];
      a += wq[0] * h[0] + wq[1] * h[1] + wq[2] * h[2] + wq[3] * h[3];
    }
    h3[t] = fmaxf(0.f, (a + b3[t]) * bninv * g2[t] + bb2[t]);
  }
  __syncthreads();
  if (t < 2) {
    const float* wr = W4 + t * 128;
    float a = 0.f;
#pragma unroll 4
    for (int i = 0; i < 128; ++i) a += wr[i] * h3[i];
    out[b * 2 + t] = a + b4[t];
  }
}

extern "C" void kernel_launch(void* const* d_in, const int* in_sizes, int n_in,
                              void* d_out, int out_size, void* d_ws, size_t ws_size,
                              hipStream_t stream) {
  const float* x   = (const float*)d_in[0];
  const float* W1  = (const float*)d_in[1];
  const float* b1  = (const float*)d_in[2];
  const float* lng = (const float*)d_in[3];
  const float* lnb = (const float*)d_in[4];
  const float* W2  = (const float*)d_in[5];
  const float* b2  = (const float*)d_in[6];
  const float* g1  = (const float*)d_in[7];
  const float* bb1 = (const float*)d_in[8];
  const float* W3  = (const float*)d_in[9];
  const float* b3  = (const float*)d_in[10];
  const float* g2  = (const float*)d_in[11];
  const float* bb2 = (const float*)d_in[12];
  const float* W4  = (const float*)d_in[13];
  const float* b4  = (const float*)d_in[14];
  float* out = (float*)d_out;

  char* ws = (char*)d_ws;
  ushort_t* mF = (ushort_t*)ws;              // 384 KB (fragment-ordered bf16 m)
  float* big   = (float*)(ws + 524288);      // split-K partials

  size_t need = 524288 + (size_t)PSPLIT * BATCH * PROJ * 4;  // ~17.3 MB
  bool partial = ws_size >= need;

  hipLaunchKernelGGL(prep_kernel, dim3(256), dim3(256), 0, stream, x, mF);
  if (partial) {
    hipLaunchKernelGGL(einsum_kernel, dim3(NT * PSPLIT), dim3(512), 0, stream,
                       W1, mF, x, big, 0);
    hipLaunchKernelGGL(mlp_kernel, dim3(BATCH), dim3(256), 0, stream, big, PSPLIT,
                       b1, lng, lnb, W2, b2, g1, bb1, W3, b3, g2, bb2, W4, b4, out);
  } else {
    hipMemsetAsync(big, 0, (size_t)BATCH * PROJ * 4, stream);
    hipLaunchKernelGGL(einsum_kernel, dim3(NT * PSPLIT), dim3(512), 0, stream,
                       W1, mF, x, big, 1);
    hipLaunchKernelGGL(mlp_kernel, dim3(BATCH), dim3(256), 0, stream, big, 1,
                       b1, lng, lnb, W2, b2, g1, bb1, W3, b3, g2, bb2, W4, b4, out);
  }
}